// Round 7
// baseline (909.988 us; speedup 1.0000x reference)
//
#include <hip/hip_runtime.h>
#include <stdint.h>

typedef __attribute__((ext_vector_type(8))) short short8;
typedef __attribute__((ext_vector_type(4))) float f32x4;

#define MFMA16 __builtin_amdgcn_mfma_f32_16x16x32_bf16
#define PFENCE() asm volatile("" ::: "memory")

static constexpr int kNodes  = 262144;
static constexpr int kOutD   = 320;
static constexpr int THREADS = 256;                // 4 waves
static constexpr int NBLOCKS = 512;                // 2 blocks/CU resident
static constexpr int WTILES  = kNodes / 16;        // 16384 wave-tiles
static constexpr int NWAVES  = NBLOCKS * 4;        // 2048
static constexpr int ITERS   = WTILES / NWAVES;    // 8

// ---- d_ws layout (uint16 units): bf16 MFMA-fragment-packed weights ----
static constexpr int W1F_O = 0;       // 48 frags (ht*4+kt) x 64 lanes x 8
static constexpr int W2F_O = 24576;   // 32 frags (ot*4+kt)
static constexpr int V1F_O = 40960;   // 8 frags (jt*2+kt)
static constexpr int V2F_O = 45056;   // 8 frags

// ---- LDS: biases + 4 x 18432B wave-private scratch (NO overlays) ----
static constexpr int B1O  = 0;        // 192 f32
static constexpr int B2O  = 768;      // 128 f32
static constexpr int BUF0 = 1536;
static constexpr int XV = 0;          // 48 rows x 128B   x_v tile (rr=3n+c)
static constexpr int SC = 6144;       // 16 rows x 256B   scal bf16
static constexpr int GT = 10240;      // 16 rows x 128B   gates bf16
static constexpr int VG = 12288;      // 48 rows x 128B   gated vectors
static constexpr int WBUF = 18432;
static constexpr int SMEM_BYTES = BUF0 + 4 * WBUF;   // 75264 -> 2 blocks/CU

__device__ __forceinline__ uint16_t f2bf(float f) {
  uint32_t u = __builtin_bit_cast(uint32_t, f);
  u += 0x7FFFu + ((u >> 16) & 1u);          // RNE
  return (uint16_t)(u >> 16);
}
__device__ __forceinline__ float bf2f(uint16_t u) {
  return __builtin_bit_cast(float, ((uint32_t)u) << 16);
}
__device__ __forceinline__ short8 pack8(const float4& a, const float4& b) {
  short8 r;
  r[0] = (short)f2bf(a.x); r[1] = (short)f2bf(a.y);
  r[2] = (short)f2bf(a.z); r[3] = (short)f2bf(a.w);
  r[4] = (short)f2bf(b.x); r[5] = (short)f2bf(b.y);
  r[6] = (short)f2bf(b.z); r[7] = (short)f2bf(b.w);
  return r;
}

// ---------- prep: pack weights into fragment order (bf16) ----------
extern "C" __global__ void pack_weights(const float* __restrict__ W1_s,
                                        const float* __restrict__ W1_v,
                                        const float* __restrict__ W2_s,
                                        const float* __restrict__ W2_v,
                                        uint16_t* __restrict__ ws)
{
  int gid = blockIdx.x * blockDim.x + threadIdx.x;   // 0..6143
  if (gid >= 96 * 64) return;
  int l = gid & 63, f = gid >> 6;
  int lw = l & 15, lg = l >> 4;
  const float* src; int ldk, col, kbase; uint16_t* dst;
  if (f < 48) {        int ht = f >> 2, kt = f & 3;
    src = W1_s; ldk = 192; col = ht * 16 + lw; kbase = kt * 32 + lg * 8;
    dst = ws + W1F_O + (size_t)(f * 64 + l) * 8;
  } else if (f < 80) { int g = f - 48, ot = g >> 2, kt = g & 3;
    src = W2_s; ldk = 128; col = ot * 16 + lw; kbase = kt * 32 + lg * 8;
    dst = ws + W2F_O + (size_t)(g * 64 + l) * 8;
  } else if (f < 88) { int g = f - 80, jt = g >> 1, kt = g & 1;
    src = W1_v; ldk = 64;  col = jt * 16 + lw; kbase = kt * 32 + lg * 8;
    dst = ws + V1F_O + (size_t)(g * 64 + l) * 8;
  } else {             int g = f - 88, jt = g >> 1, kt = g & 1;
    src = W2_v; ldk = 64;  col = jt * 16 + lw; kbase = kt * 32 + lg * 8;
    dst = ws + V2F_O + (size_t)(g * 64 + l) * 8;
  }
  alignas(16) uint16_t tmp[8];
#pragma unroll
  for (int e = 0; e < 8; ++e) tmp[e] = f2bf(src[(size_t)(kbase + e) * ldk + col]);
  *(uint4*)dst = *(const uint4*)tmp;
}

// ---------- main fused kernel: wave-autonomous, zero loop barriers ----------
extern "C" __global__ __launch_bounds__(THREADS, 2)
void fused_gate_mlp(const float* __restrict__ x_s, const float* __restrict__ x_v,
                    const float* __restrict__ b1_s, const float* __restrict__ b2_s,
                    const uint16_t* ws, float* __restrict__ out)
{
  extern __shared__ char smem[];
  const int tid = threadIdx.x;

  if (tid < 192) ((float*)(smem + B1O))[tid] = b1_s[tid];
  if (tid < 128) ((float*)(smem + B2O))[tid] = b2_s[tid];
  __syncthreads();   // only barrier

  const int w  = tid >> 6;
  const int l  = tid & 63;
  const int lw = l & 15;
  const int lg = l >> 4;
  const int sx = (lw & 7) << 4;
  char* buf = smem + BUF0 + w * WBUF;     // wave-private scratch
  const float* b1 = (const float*)(smem + B1O);
  const float* b2 = (const float*)(smem + B2O);
  const short8* W1F = (const short8*)(ws + W1F_O);
  const short8* W2F = (const short8*)(ws + W2F_O);
  const short8* V1F = (const short8*)(ws + V1F_O);
  const short8* V2F = (const short8*)(ws + V2F_O);

  const float inv_s = 0.08838834764831845f;  // 1/sqrt(128)
  const float inv_v = 0.125f;                // 1/sqrt(64)

  int wt = blockIdx.x * 4 + w;

  // ---------- prefetch x_s of iteration 0 ----------
  float4 pfx[8];
  {
    const float4* ps = (const float4*)(x_s + (size_t)wt * 2048);
#pragma unroll
    for (int kt = 0; kt < 4; ++kt) {
      pfx[2 * kt + 0] = ps[lw * 32 + kt * 8 + lg * 2 + 0];
      pfx[2 * kt + 1] = ps[lw * 32 + kt * 8 + lg * 2 + 1];
    }
  }

#pragma unroll 1
  for (int t = 0; t < ITERS; ++t) {
    const int node0 = wt * 16;
    float* orow = out + (size_t)node0 * kOutD;

    PFENCE();
    // ======== issue x_v loads (consumed after s1; ~1500cyc cover) ========
    float4 pfv[12];
    {
      const float4* pv = (const float4*)(x_v + (size_t)wt * 3072);
#pragma unroll
      for (int p = 0; p < 12; ++p) pfv[p] = pv[l + p * 64];
    }
    PFENCE();

    // ======== x_s A-fragments from prefetched regs (pfx dies) ========
    short8 axs[4];
#pragma unroll
    for (int kt = 0; kt < 4; ++kt) axs[kt] = pack8(pfx[2 * kt], pfx[2 * kt + 1]);

    // ======== s1 = x_s @ W1_s in two h-halves, activation fused ========
#pragma unroll
    for (int hh = 0; hh < 2; ++hh) {
      f32x4 accs[6];
#pragma unroll
      for (int i = 0; i < 6; ++i) accs[i] = (f32x4){0.f, 0.f, 0.f, 0.f};
#pragma unroll
      for (int kt = 0; kt < 4; ++kt)
#pragma unroll
        for (int hf = 0; hf < 6; ++hf) {
          const int ht = hh * 6 + hf;
          accs[hf] = MFMA16(axs[kt], W1F[(ht * 4 + kt) * 64 + l], accs[hf], 0, 0, 0);
        }
      PFENCE();
      // act: scal -> SC, gates -> GT (regions disjoint from XV!)
#pragma unroll
      for (int hf = 0; hf < 6; ++hf) {
        const int ht = hh * 6 + hf;
        const int h = ht * 16 + lw;
        const float bb = b1[h];
#pragma unroll
        for (int r = 0; r < 4; ++r) {
          const int n = lg * 4 + r;
          float v = accs[hf][r] * inv_s + bb;
          float sg = 1.0f / (1.0f + __expf(-v));
          if (ht < 8)
            *(uint16_t*)(buf + SC + n * 256 + ((2 * h) ^ ((n & 7) << 4))) = f2bf(v * sg);
          else
            *(uint16_t*)(buf + GT + n * 128 + 2 * ((ht - 8) * 16 + lw)) = f2bf(sg);
        }
      }
      PFENCE();
    }

    // ======== issue x_s prefetch for NEXT tile ========
    const int nwt = (wt + NWAVES) & (WTILES - 1);
    {
      const float4* ps = (const float4*)(x_s + (size_t)nwt * 2048);
#pragma unroll
      for (int kt = 0; kt < 4; ++kt) {
        pfx[2 * kt + 0] = ps[lw * 32 + kt * 8 + lg * 2 + 0];
        pfx[2 * kt + 1] = ps[lw * 32 + kt * 8 + lg * 2 + 1];
      }
    }
    PFENCE();

    // ======== stage x_v -> XV rows [rr=3n+c][i] (bf16, swizzled) ========
#pragma unroll
    for (int p = 0; p < 12; ++p) {
      unsigned idx4 = (unsigned)l + p * 64;
      unsigned n = idx4 / 48, rem = idx4 - n * 48;
      float v[4] = {pfv[p].x, pfv[p].y, pfv[p].z, pfv[p].w};
#pragma unroll
      for (int e = 0; e < 4; ++e) {
        unsigned fe = rem * 4 + e, i = fe / 3, c = fe - i * 3, rr = n * 3 + c;
        *(uint16_t*)(buf + XV + rr * 128 + ((2 * i) ^ ((rr & 7) << 4))) = f2bf(v[e]);
      }
    }

    // ======== x_v A-fragments ========
    short8 axv[3][2];
#pragma unroll
    for (int m2 = 0; m2 < 3; ++m2)
#pragma unroll
      for (int kt = 0; kt < 2; ++kt)
        axv[m2][kt] = *(const short8*)(buf + XV + (m2 * 16 + lw) * 128 + ((kt * 64 + lg * 16) ^ sx));

    // ======== v1 in two jt-halves, v_g fused per half ========
#pragma unroll
    for (int jh = 0; jh < 2; ++jh) {
      f32x4 accv[6];
#pragma unroll
      for (int i = 0; i < 6; ++i) accv[i] = (f32x4){0.f, 0.f, 0.f, 0.f};
#pragma unroll
      for (int kt = 0; kt < 2; ++kt)
#pragma unroll
        for (int jf = 0; jf < 2; ++jf) {
          const int jt = jh * 2 + jf;
          short8 b = V1F[(jt * 2 + kt) * 64 + l];
#pragma unroll
          for (int m2 = 0; m2 < 3; ++m2)
            accv[m2 * 2 + jf] = MFMA16(axv[m2][kt], b, accv[m2 * 2 + jf], 0, 0, 0);
        }
      PFENCE();
      // v_g = v1 * gate -> VG (GT and VG disjoint: no preload tricks)
#pragma unroll
      for (int m2 = 0; m2 < 3; ++m2)
#pragma unroll
        for (int r = 0; r < 4; ++r) {
          const unsigned rr = m2 * 16 + lg * 4 + r;
          const unsigned n = rr / 3;
#pragma unroll
          for (int jf = 0; jf < 2; ++jf) {
            const int j = (jh * 2 + jf) * 16 + lw;
            const float g = bf2f(*(const uint16_t*)(buf + GT + n * 128 + 2 * j));
            float vgv = accv[m2 * 2 + jf][r] * inv_v * g;
            *(uint16_t*)(buf + VG + rr * 128 + ((2 * j) ^ ((rr & 7) << 4))) = f2bf(vgv);
          }
        }
      PFENCE();
    }

    // ======== out_s = scal @ W2_s, store ========
    {
      short8 as2[4];
#pragma unroll
      for (int kt = 0; kt < 4; ++kt)
        as2[kt] = *(const short8*)(buf + SC + lw * 256 + ((kt * 64 + lg * 16) ^ sx));
      f32x4 acco[8];
#pragma unroll
      for (int i = 0; i < 8; ++i) acco[i] = (f32x4){0.f, 0.f, 0.f, 0.f};
#pragma unroll
      for (int kt = 0; kt < 4; ++kt)
#pragma unroll
        for (int ot = 0; ot < 8; ++ot)
          acco[ot] = MFMA16(as2[kt], W2F[(ot * 4 + kt) * 64 + l], acco[ot], 0, 0, 0);
#pragma unroll
      for (int ot = 0; ot < 8; ++ot) {
        const int o = ot * 16 + lw;
        const float bb = b2[o];
#pragma unroll
        for (int r = 0; r < 4; ++r)
          orow[(size_t)(lg * 4 + r) * kOutD + o] = acco[ot][r] * inv_s + bb;
      }
    }
    PFENCE();

    // ======== out_v = v_g . W2_v in two jt-halves, store ========
    {
      short8 avg_[3][2];
#pragma unroll
      for (int m2 = 0; m2 < 3; ++m2)
#pragma unroll
        for (int kt = 0; kt < 2; ++kt)
          avg_[m2][kt] = *(const short8*)(buf + VG + (m2 * 16 + lw) * 128 + ((kt * 64 + lg * 16) ^ sx));
#pragma unroll
      for (int jh = 0; jh < 2; ++jh) {
        f32x4 accw[6];
#pragma unroll
        for (int i = 0; i < 6; ++i) accw[i] = (f32x4){0.f, 0.f, 0.f, 0.f};
#pragma unroll
        for (int kt = 0; kt < 2; ++kt)
#pragma unroll
          for (int jf = 0; jf < 2; ++jf) {
            const int jt = jh * 2 + jf;
            short8 b = V2F[(jt * 2 + kt) * 64 + l];
#pragma unroll
            for (int m2 = 0; m2 < 3; ++m2)
              accw[m2 * 2 + jf] = MFMA16(avg_[m2][kt], b, accw[m2 * 2 + jf], 0, 0, 0);
          }
#pragma unroll
        for (int m2 = 0; m2 < 3; ++m2)
#pragma unroll
          for (int r = 0; r < 4; ++r) {
            const unsigned rr = m2 * 16 + lg * 4 + r;
            const unsigned n = rr / 3, c = rr - 3 * n;
#pragma unroll
            for (int jf = 0; jf < 2; ++jf) {
              const int j2 = (jh * 2 + jf) * 16 + lw;
              orow[(size_t)n * kOutD + 128 + j2 * 3 + c] = accw[m2 * 2 + jf][r] * inv_v;
            }
          }
      }
    }

    wt = nwt;
  }
}

extern "C" void kernel_launch(void* const* d_in, const int* in_sizes, int n_in,
                              void* d_out, int out_size, void* d_ws, size_t ws_size,
                              hipStream_t stream) {
  const float* x_s  = (const float*)d_in[0];
  const float* x_v  = (const float*)d_in[1];
  const float* W1_s = (const float*)d_in[2];
  const float* b1_s = (const float*)d_in[3];
  const float* W1_v = (const float*)d_in[4];
  const float* W2_s = (const float*)d_in[5];
  const float* b2_s = (const float*)d_in[6];
  const float* W2_v = (const float*)d_in[7];
  uint16_t* ws = (uint16_t*)d_ws;
  float* o = (float*)d_out;

  hipLaunchKernelGGL(pack_weights, dim3(12), dim3(512), 0, stream,
                     W1_s, W1_v, W2_s, W2_v, ws);
  hipLaunchKernelGGL(fused_gate_mlp, dim3(NBLOCKS), dim3(THREADS), SMEM_BYTES, stream,
                     x_s, x_v, b1_s, b2_s, ws, o);
}

// Round 8
// 389.467 us; speedup vs baseline: 2.3365x; 2.3365x over previous
//
#include <hip/hip_runtime.h>
#include <stdint.h>

typedef __attribute__((ext_vector_type(8))) short short8;
typedef __attribute__((ext_vector_type(4))) float f32x4;

#define MFMA16 __builtin_amdgcn_mfma_f32_16x16x32_bf16
#define PFENCE() asm volatile("" ::: "memory")

static constexpr int kNodes  = 262144;
static constexpr int kOutD   = 320;
static constexpr int THREADS = 512;               // 8 waves, 1 block/CU
static constexpr int NBLOCKS = 256;
static constexpr int WTILES  = kNodes / 16;       // 16384 wave-tiles
static constexpr int NWAVES  = NBLOCKS * 8;       // 2048
static constexpr int ITERS   = WTILES / NWAVES;   // 8

// ---- LDS byte offsets (R1-proven layout) ----
static constexpr int W1S  = 0;       // [192][256B]  W1_s^T (row h, col k), swizzled
static constexpr int W2S  = 49152;   // [128][256B]  W2_s^T (row o, col h), swizzled
static constexpr int W1V  = 81920;   // [64][128B]   W1_v^T (row j, col i), swizzled
static constexpr int W2V  = 90112;   // [64][128B]   W2_v^T
static constexpr int B1O  = 98304;   // 192 f32
static constexpr int B2O  = 99072;   // 128 f32
static constexpr int BUF0 = 99584;   // 8 waves x 6144B private overlay scratch
static constexpr int SMEM_BYTES = BUF0 + 8 * 6144;   // 148736

__device__ __forceinline__ uint16_t f2bf(float f) {
  uint32_t u = __builtin_bit_cast(uint32_t, f);
  u += 0x7FFFu + ((u >> 16) & 1u);          // RNE
  return (uint16_t)(u >> 16);
}
__device__ __forceinline__ float bf2f(uint16_t u) {
  return __builtin_bit_cast(float, ((uint32_t)u) << 16);
}
__device__ __forceinline__ short8 pack8(const float4& a, const float4& b) {
  short8 r;
  r[0] = (short)f2bf(a.x); r[1] = (short)f2bf(a.y);
  r[2] = (short)f2bf(a.z); r[3] = (short)f2bf(a.w);
  r[4] = (short)f2bf(b.x); r[5] = (short)f2bf(b.y);
  r[6] = (short)f2bf(b.z); r[7] = (short)f2bf(b.w);
  return r;
}

extern "C" __global__ __launch_bounds__(THREADS, 2)
void fused_gate_mlp(const float* __restrict__ x_s, const float* __restrict__ x_v,
                    const float* __restrict__ W1_s, const float* __restrict__ b1_s,
                    const float* __restrict__ W1_v, const float* __restrict__ W2_s,
                    const float* __restrict__ b2_s, const float* __restrict__ W2_v,
                    float* __restrict__ out)
{
  extern __shared__ char smem[];
  const int tid = threadIdx.x;

  // ---------- stage weights once (R1-proven), single barrier ----------
  for (int idx = tid; idx < 128 * 192; idx += THREADS) {       // W1_s [k][h] -> [h][k]
    int k = idx / 192, h = idx - k * 192;
    *(uint16_t*)(smem + W1S + h * 256 + ((2 * k) ^ ((h & 7) << 4))) = f2bf(W1_s[idx]);
  }
  for (int idx = tid; idx < 128 * 128; idx += THREADS) {       // W2_s [h][o] -> [o][h]
    int k = idx >> 7, o = idx & 127;
    *(uint16_t*)(smem + W2S + o * 256 + ((2 * k) ^ ((o & 7) << 4))) = f2bf(W2_s[idx]);
  }
  for (int idx = tid; idx < 64 * 64; idx += THREADS) {         // W1_v/W2_v [i][j] -> [j][i]
    int i = idx >> 6, j = idx & 63;
    int off = j * 128 + ((2 * i) ^ ((j & 7) << 4));
    *(uint16_t*)(smem + W1V + off) = f2bf(W1_v[idx]);
    *(uint16_t*)(smem + W2V + off) = f2bf(W2_v[idx]);
  }
  if (tid < 192) ((float*)(smem + B1O))[tid] = b1_s[tid];
  if (tid < 128) ((float*)(smem + B2O))[tid] = b2_s[tid];
  __syncthreads();   // only barrier

  const int w  = tid >> 6;
  const int l  = tid & 63;
  const int lw = l & 15;
  const int lg = l >> 4;
  const int sx = (lw & 7) << 4;
  char* buf = smem + BUF0 + w * 6144;     // wave-private overlay scratch
  const float* b1 = (const float*)(smem + B1O);
  const float* b2 = (const float*)(smem + B2O);

  const float inv_s = 0.08838834764831845f;  // 1/sqrt(128)
  const float inv_v = 0.125f;                // 1/sqrt(64)

  int wt = blockIdx.x * 8 + w;

  // ---------- prime: x_s of tile 0 ----------
  float4 pfx[8];
  {
    const float4* ps = (const float4*)(x_s + (size_t)wt * 2048);
#pragma unroll
    for (int kt = 0; kt < 4; ++kt) {
      pfx[2 * kt + 0] = ps[lw * 32 + kt * 8 + lg * 2 + 0];
      pfx[2 * kt + 1] = ps[lw * 32 + kt * 8 + lg * 2 + 1];
    }
  }

#pragma unroll 1
  for (int t = 0; t < ITERS; ++t) {
    const int node0 = wt * 16;
    float* orow = out + (size_t)node0 * kOutD;

    // ---- A: pack x_s A-fragments (pfx dies -> 16 regs) ----
    short8 axs[4];
#pragma unroll
    for (int kt = 0; kt < 4; ++kt) axs[kt] = pack8(pfx[2 * kt], pfx[2 * kt + 1]);

    PFENCE();
    // ---- B: issue x_v loads; latency hidden under s1 (48 MFMA) ----
    float4 pfv[12];
    {
      const float4* pv = (const float4*)(x_v + (size_t)wt * 3072);
#pragma unroll
      for (int p = 0; p < 12; ++p) pfv[p] = pv[l + p * 64];
    }
    PFENCE();

    // ---- C/D: s1 = x_s @ W1_s, both halves (accs in AGPRs) ----
    f32x4 accs0[6], accs1[6];
#pragma unroll
    for (int i = 0; i < 6; ++i) { accs0[i] = (f32x4){0.f,0.f,0.f,0.f}; accs1[i] = (f32x4){0.f,0.f,0.f,0.f}; }
#pragma unroll
    for (int kt = 0; kt < 4; ++kt) {
      const int kb = (kt * 64 + lg * 16) ^ sx;
#pragma unroll
      for (int hf = 0; hf < 6; ++hf) {
        short8 b = *(const short8*)(smem + W1S + (hf * 16 + lw) * 256 + kb);
        accs0[hf] = MFMA16(axs[kt], b, accs0[hf], 0, 0, 0);
      }
#pragma unroll
      for (int hf = 0; hf < 6; ++hf) {
        short8 b = *(const short8*)(smem + W1S + ((6 + hf) * 16 + lw) * 256 + kb);
        accs1[hf] = MFMA16(axs[kt], b, accs1[hf], 0, 0, 0);
      }
    }

    PFENCE();
    // ---- E: stage x_v -> XV rows [rr=3n+c][i] (pfv dies) ----
#pragma unroll
    for (int p = 0; p < 12; ++p) {
      unsigned idx4 = (unsigned)l + p * 64;
      unsigned n = idx4 / 48, rem = idx4 - n * 48;
      float v[4] = {pfv[p].x, pfv[p].y, pfv[p].z, pfv[p].w};
#pragma unroll
      for (int e = 0; e < 4; ++e) {
        unsigned fe = rem * 4 + e, i = fe / 3, c = fe - i * 3, rr = n * 3 + c;
        *(uint16_t*)(buf + rr * 128 + ((2 * i) ^ ((rr & 7) << 4))) = f2bf(v[e]);
      }
    }

    // ---- F: x_v A-fragments to regs (XV dies) ----
    short8 axv[3][2];
#pragma unroll
    for (int m2 = 0; m2 < 3; ++m2)
#pragma unroll
      for (int kt = 0; kt < 2; ++kt)
        axv[m2][kt] = *(const short8*)(buf + (m2 * 16 + lw) * 128 + ((kt * 64 + lg * 16) ^ sx));

    PFENCE();
    // ---- G: activation -> scal[0..4K) + gates[4K..6K) (accs die) ----
#pragma unroll
    for (int ht = 0; ht < 12; ++ht) {
      const int h = ht * 16 + lw;
      const float bb = b1[h];
      const f32x4 a = (ht < 6) ? accs0[ht] : accs1[ht - 6];
#pragma unroll
      for (int r = 0; r < 4; ++r) {
        const int n = lg * 4 + r;
        float v = a[r] * inv_s + bb;
        float sg = 1.0f / (1.0f + __expf(-v));
        if (ht < 8)
          *(uint16_t*)(buf + n * 256 + ((2 * h) ^ ((n & 7) << 4))) = f2bf(v * sg);
        else
          *(uint16_t*)(buf + 4096 + n * 128 + 2 * ((ht - 8) * 16 + lw)) = f2bf(sg);
      }
    }

    // ---- H: scal A-fragments (before VG clobbers bytes 0..4K) ----
    short8 as2[4];
#pragma unroll
    for (int kt = 0; kt < 4; ++kt)
      as2[kt] = *(const short8*)(buf + lw * 256 + ((kt * 64 + lg * 16) ^ sx));

    // ---- I: v1 = x_v . W1_v ----
    f32x4 accv[12];
#pragma unroll
    for (int i = 0; i < 12; ++i) accv[i] = (f32x4){0.f, 0.f, 0.f, 0.f};
#pragma unroll
    for (int kt = 0; kt < 2; ++kt) {
      const int kb = (kt * 64 + lg * 16) ^ sx;
#pragma unroll
      for (int jt = 0; jt < 4; ++jt) {
        short8 b = *(const short8*)(smem + W1V + (jt * 16 + lw) * 128 + kb);
#pragma unroll
        for (int m2 = 0; m2 < 3; ++m2)
          accv[m2 * 4 + jt] = MFMA16(axv[m2][kt], b, accv[m2 * 4 + jt], 0, 0, 0);
      }
    }

    PFENCE();
    // ---- J: v_g -> VG rows (m2=0,1 direct; m2=2 via gate preload) ----
#pragma unroll
    for (int m2 = 0; m2 < 2; ++m2)
#pragma unroll
      for (int r = 0; r < 4; ++r) {
        const unsigned rr = m2 * 16 + lg * 4 + r;
        const unsigned n = rr / 3;
#pragma unroll
        for (int jt = 0; jt < 4; ++jt) {
          const int j = jt * 16 + lw;
          const float g = bf2f(*(const uint16_t*)(buf + 4096 + n * 128 + 2 * j));
          float vgv = accv[m2 * 4 + jt][r] * inv_v * g;
          *(uint16_t*)(buf + rr * 128 + ((2 * j) ^ ((rr & 7) << 4))) = f2bf(vgv);
        }
      }
    {
      float g2[4][4];
#pragma unroll
      for (int r = 0; r < 4; ++r) {
        const unsigned rr = 32 + lg * 4 + r, n = rr / 3;
#pragma unroll
        for (int jt = 0; jt < 4; ++jt)
          g2[r][jt] = bf2f(*(const uint16_t*)(buf + 4096 + n * 128 + 2 * (jt * 16 + lw)));
      }
#pragma unroll
      for (int r = 0; r < 4; ++r) {
        const unsigned rr = 32 + lg * 4 + r;
#pragma unroll
        for (int jt = 0; jt < 4; ++jt) {
          const int j = jt * 16 + lw;
          float vgv = accv[8 + jt][r] * inv_v * g2[r][jt];
          *(uint16_t*)(buf + rr * 128 + ((2 * j) ^ ((rr & 7) << 4))) = f2bf(vgv);
        }
      }
    }

    PFENCE();
    // ---- K: issue x_s prefetch for NEXT tile (covered by out_s/out_v) ----
    const int nwt = (wt + NWAVES) & (WTILES - 1);
    {
      const float4* ps = (const float4*)(x_s + (size_t)nwt * 2048);
#pragma unroll
      for (int kt = 0; kt < 4; ++kt) {
        pfx[2 * kt + 0] = ps[lw * 32 + kt * 8 + lg * 2 + 0];
        pfx[2 * kt + 1] = ps[lw * 32 + kt * 8 + lg * 2 + 1];
      }
    }
    PFENCE();

    // ---- L: out_s = scal @ W2_s, store ----
    {
      f32x4 acco[8];
#pragma unroll
      for (int i = 0; i < 8; ++i) acco[i] = (f32x4){0.f, 0.f, 0.f, 0.f};
#pragma unroll
      for (int kt = 0; kt < 4; ++kt) {
        const int kb = (kt * 64 + lg * 16) ^ sx;
#pragma unroll
        for (int ot = 0; ot < 8; ++ot) {
          short8 b = *(const short8*)(smem + W2S + (ot * 16 + lw) * 256 + kb);
          acco[ot] = MFMA16(as2[kt], b, acco[ot], 0, 0, 0);
        }
      }
#pragma unroll
      for (int ot = 0; ot < 8; ++ot) {
        const int o = ot * 16 + lw;
        const float bb = b2[o];
#pragma unroll
        for (int r = 0; r < 4; ++r)
          orow[(size_t)(lg * 4 + r) * kOutD + o] = acco[ot][r] * inv_s + bb;
      }
    }

    PFENCE();
    // ---- M: out_v = v_g . W2_v, store ----
    {
      short8 avg_[3][2];
#pragma unroll
      for (int m2 = 0; m2 < 3; ++m2)
#pragma unroll
        for (int kt = 0; kt < 2; ++kt)
          avg_[m2][kt] = *(const short8*)(buf + (m2 * 16 + lw) * 128 + ((kt * 64 + lg * 16) ^ sx));
      f32x4 accw[12];
#pragma unroll
      for (int i = 0; i < 12; ++i) accw[i] = (f32x4){0.f, 0.f, 0.f, 0.f};
#pragma unroll
      for (int kt = 0; kt < 2; ++kt) {
        const int kb = (kt * 64 + lg * 16) ^ sx;
#pragma unroll
        for (int jt = 0; jt < 4; ++jt) {
          short8 b = *(const short8*)(smem + W2V + (jt * 16 + lw) * 128 + kb);
#pragma unroll
          for (int m2 = 0; m2 < 3; ++m2)
            accw[m2 * 4 + jt] = MFMA16(avg_[m2][kt], b, accw[m2 * 4 + jt], 0, 0, 0);
        }
      }
#pragma unroll
      for (int m2 = 0; m2 < 3; ++m2)
#pragma unroll
        for (int r = 0; r < 4; ++r) {
          const unsigned rr = m2 * 16 + lg * 4 + r;
          const unsigned n = rr / 3, c = rr - 3 * n;
#pragma unroll
          for (int jt = 0; jt < 4; ++jt)
            orow[(size_t)n * kOutD + 128 + (jt * 16 + lw) * 3 + c] = accw[m2 * 4 + jt][r] * inv_v;
        }
    }

    wt = nwt;
  }
}

extern "C" void kernel_launch(void* const* d_in, const int* in_sizes, int n_in,
                              void* d_out, int out_size, void* d_ws, size_t ws_size,
                              hipStream_t stream) {
  const float* x_s  = (const float*)d_in[0];
  const float* x_v  = (const float*)d_in[1];
  const float* W1_s = (const float*)d_in[2];
  const float* b1_s = (const float*)d_in[3];
  const float* W1_v = (const float*)d_in[4];
  const float* W2_s = (const float*)d_in[5];
  const float* b2_s = (const float*)d_in[6];
  const float* W2_v = (const float*)d_in[7];
  float* o = (float*)d_out;
  hipLaunchKernelGGL(fused_gate_mlp, dim3(NBLOCKS), dim3(THREADS), SMEM_BYTES, stream,
                     x_s, x_v, W1_s, b1_s, W1_v, W2_s, b2_s, W2_v, o);
}